// Round 7
// baseline (187.144 us; speedup 1.0000x reference)
//
#include <hip/hip_runtime.h>

// ResGCNBlock: out = LN(relu(scatter_add(norm * (xW^T+b)[row] -> col))) + x
// N=50000, D=128, E=800000, fp32.
// Round 17: dual-row k_agg. r12-r16 micro-tuning was noise-level; r11 PMC
//   (k_agg 44us, 2.75TB/s, VALU 47%) says outstanding-miss x latency bound:
//   per wave only 1 srcs2 load + 4 gathers in flight, then a serial ~300cy
//   epilogue. Fix: one wave owns TWO adjacent dest rows -> 2 independent
//   chains interleaved (2 srcs2 + 8 gathers in flight; B's gathers hide A's
//   epilogue). Self-loops on quads 0/1, stores from quads 0/1 in parallel.
//   Shuffles stay full-wave w/ self-masking pads (r10 invariant).
//   History: global atomics dead on gfx950 (r4/r7) -> LDS histograms (r8);
//   __shfl from inactive lanes UNDEFINED -> wave-uniform trips (r10);
//   NT streams (r11); 4-wide load groups (r12, best=177.6); premul srcs2
//   (r13-15); predication+occupancy pin (r16, neutral).

#define D 128
#define CHSH 15                      // chunk = 32768 edges per hist block
#define CHUNK (1 << CHSH)
#define NWORD 12500                  // ceil(50000/4) packed-byte LDS words

typedef short bf16x8 __attribute__((ext_vector_type(8)));
typedef float f32x4 __attribute__((ext_vector_type(4)));

__device__ __forceinline__ unsigned short f2bf(float f) {
    unsigned u = __float_as_uint(f);
    return (unsigned short)((u + 0x7fffu + ((u >> 16) & 1u)) >> 16);
}
__device__ __forceinline__ float bf2f_lo(unsigned v) { return __uint_as_float(v << 16); }
__device__ __forceinline__ float bf2f_hi(unsigned v) { return __uint_as_float(v & 0xffff0000u); }

// ---------- merged (1024-thr): cnt-hist [0,K) + deg-hist [K,2K) + GEMM rest ----------
__global__ void __launch_bounds__(1024)
k_gemm_hist(const float* __restrict__ x, const float* __restrict__ W,
            const float* __restrict__ bias, unsigned short* __restrict__ hb,
            int nrows,
            const int* __restrict__ ei, int E, int n,
            unsigned char* __restrict__ degc, unsigned char* __restrict__ cntc,
            unsigned char* __restrict__ aux, int K) {
    __shared__ unsigned sm[NWORD];                 // 50 KB: hist OR W-frag staging
    int bid = blockIdx.x;
    if (bid < 2 * K) {
        unsigned* hist = sm;
        bool is_cnt = bid < K;
        int c = is_cnt ? bid : bid - K;
        const int* vs = is_cnt ? (ei + E) : ei;    // dest for cnt, source for deg
        for (int i = threadIdx.x; i < NWORD; i += 1024) hist[i] = 0u;
        __syncthreads();
        int e0 = c << CHSH;
        int e1 = e0 + CHUNK; if (e1 > E) e1 = E;
        if (is_cnt) {
            for (int e = e0 + threadIdx.x; e < e1; e += 1024) {
                int v = vs[e];
                unsigned sh = (v & 3) * 8;
                unsigned old = atomicAdd(&hist[v >> 2], 1u << sh);
                aux[e] = (unsigned char)(old >> sh);   // rank within (chunk, dest)
            }
        } else {
            for (int e = e0 + threadIdx.x; e < e1; e += 1024) {
                int v = vs[e];
                atomicAdd(&hist[v >> 2], 1u << ((v & 3) * 8));
            }
        }
        __syncthreads();
        unsigned* dst = (unsigned*)((is_cnt ? cntc : degc) + (size_t)c * n);
        for (int i = threadIdx.x; i < NWORD; i += 1024) dst[i] = hist[i];
    } else {
        // ---- GEMM role: 16 waves, 256 rows per block ----
        unsigned short* wf = (unsigned short*)sm;
        for (int s = threadIdx.x; s < D * D; s += 1024) {
            int j  = s & 7;
            int ln = (s >> 3) & 63;
            int g  = s >> 9;                       // nt*4 + kt
            int kt = g & 3, nt = g >> 2;
            int rw = nt * 16 + (ln & 15);
            int cl = kt * 32 + (ln >> 4) * 8 + j;
            wf[s] = f2bf(W[rw * D + cl]);
        }
        __syncthreads();

        int wid = threadIdx.x >> 6, lane = threadIdx.x & 63;
        int m0 = (bid - 2 * K) * 256 + wid * 16;
        if (m0 >= nrows) return;
        int lo16 = lane & 15, quad = lane >> 4;
        const float* arow = x + (size_t)(m0 + lo16) * D + quad * 8;
        bf16x8 a[4];
        #pragma unroll
        for (int kt = 0; kt < 4; kt++) {
            float4 p = *(const float4*)(arow + kt * 32);
            float4 q = *(const float4*)(arow + kt * 32 + 4);
            bf16x8 av;
            av[0] = (short)f2bf(p.x); av[1] = (short)f2bf(p.y);
            av[2] = (short)f2bf(p.z); av[3] = (short)f2bf(p.w);
            av[4] = (short)f2bf(q.x); av[5] = (short)f2bf(q.y);
            av[6] = (short)f2bf(q.z); av[7] = (short)f2bf(q.w);
            a[kt] = av;
        }
        const bf16x8* wfv = (const bf16x8*)sm;
        #pragma unroll
        for (int nt = 0; nt < 8; nt++) {
            int n0 = nt * 16;
            float bj = bias[n0 + lo16];
            f32x4 acc = {bj, bj, bj, bj};
            #pragma unroll
            for (int kt = 0; kt < 4; kt++) {
                bf16x8 b = wfv[(nt * 4 + kt) * 64 + lane];
                acc = __builtin_amdgcn_mfma_f32_16x16x32_bf16(a[kt], b, acc, 0, 0, 0);
            }
            #pragma unroll
            for (int r = 0; r < 4; r++) {
                int gr = m0 + quad * 4 + r;
                hb[(size_t)gr * D + n0 + lo16] = f2bf(acc[r]);
            }
        }
    }
}

// ---------- reduce byte-copies (dis, cnt) + per-block partial sums of cnt ----------
__global__ void k_partial(const unsigned char* __restrict__ degc,
                          const unsigned char* __restrict__ cntc,
                          float* __restrict__ dis, unsigned* __restrict__ cnt,
                          unsigned* __restrict__ partial, int n, int K) {
    __shared__ unsigned s[256];
    int t = threadIdx.x;
    int i = blockIdx.x * 256 + t;
    unsigned tot = 0;
    if (i < n) {
        unsigned d = 0;
        for (int c = 0; c < K; c++)
            d += __builtin_nontemporal_load(degc + (size_t)c * n + i);  // read-once
        dis[i] = rsqrtf((float)d + 1.0f);          // +1 = self loop
        for (int c = 0; c < K; c++) tot += cntc[(size_t)c * n + i];     // re-read in rowptrc
        cnt[i] = tot;
    }
    s[t] = tot;
    __syncthreads();
    #pragma unroll
    for (int d = 128; d > 0; d >>= 1) {
        if (t < d) s[t] += s[t + d];
        __syncthreads();
    }
    if (t == 0) partial[blockIdx.x] = s[0];
}

// ---------- rowptr + per-copy rowptr; partials scanned redundantly per block ----------
__global__ void k_rowptrc(const unsigned* __restrict__ cnt, const unsigned char* __restrict__ cntc,
                          const unsigned* __restrict__ partial, int n, int E,
                          int* __restrict__ rowptr, int* __restrict__ rowptrc, int K, int nb) {
    __shared__ unsigned ps[256];
    __shared__ unsigned base_sh;
    int t = threadIdx.x;
    // inline exclusive scan of block partials (nb <= 256): replaces k_scanp
    unsigned pv = (t < nb) ? partial[t] : 0u;
    ps[t] = pv;
    __syncthreads();
    #pragma unroll
    for (int d = 1; d < 256; d <<= 1) {
        unsigned u = (t >= d) ? ps[t - d] : 0u;
        __syncthreads();
        ps[t] += u;
        __syncthreads();
    }
    if (t == blockIdx.x) base_sh = ps[t] - pv;     // exclusive prefix for this block
    __syncthreads();
    unsigned bbase = base_sh;
    // per-node scan within block
    int i = blockIdx.x * 256 + t;
    unsigned v = (i < n) ? cnt[i] : 0u;
    ps[t] = v;
    __syncthreads();
    #pragma unroll
    for (int d = 1; d < 256; d <<= 1) {
        unsigned u = (t >= d) ? ps[t - d] : 0u;
        __syncthreads();
        ps[t] += u;
        __syncthreads();
    }
    if (i < n) {
        int base = (int)(bbase + ps[t] - v);
        rowptr[i] = base;
        unsigned run = 0;
        for (int c = 0; c < K; c++) {
            rowptrc[(size_t)c * n + i] = base + (int)run;
            run += cntc[(size_t)c * n + i];
        }
    }
    if (blockIdx.x == 0 && t == 0) rowptr[n] = E;
}

// ---------- atomic-free bucket fill; packs {src, dis[r]*dis[v]} per edge ----------
__global__ void k_fill(const int* __restrict__ ei, int E, int n,
                       const int* __restrict__ rowptrc, const unsigned char* __restrict__ aux,
                       const float* __restrict__ dis, long long* __restrict__ srcs2) {
    int e = blockIdx.x * 256 + threadIdx.x;
    if (e < E) {
        int r = __builtin_nontemporal_load(ei + e);          // read-once
        int v = __builtin_nontemporal_load(ei + E + e);      // read-once
        int c = e >> CHSH;
        int rank = __builtin_nontemporal_load(aux + e);      // read-once
        float w = dis[r] * dis[v];                 // same fp32 product as before
        long long p = (long long)(unsigned)r |
                      ((long long)(unsigned)__float_as_uint(w) << 32);
        srcs2[rowptrc[(size_t)c * n + v] + rank] = p;        // 8B scatter
    }
}

// ---------- fused gather-aggregate + self-loop + relu + LN + residual ----------
// ONE WAVE = TWO ADJACENT DEST ROWS (rA, rB=rA+1). Each row: quad j handles
// edges j (mod 4), lane t owns cols 8t..8t+7. Two independent chains ->
// 2 srcs2 loads + 8 hb gathers in flight per wave; B's gathers overlap A's
// epilogue. Self-loop A on quad 0, B on quad 1; stores from quads 0/1.
// All trip counts wave-uniform; all shuffles full-wave (inactive-lane
// shuffle UNDEFINED on gfx950); pad lanes carry sv=0/w=0 and self-mask.
__global__ void __launch_bounds__(256, 2)
k_agg(const float* __restrict__ x, const unsigned short* __restrict__ hb,
      const float* __restrict__ dis,
      const int* __restrict__ rowptr, const long long* __restrict__ srcs2,
      const float* __restrict__ gamma, const float* __restrict__ beta,
      float* __restrict__ out, int n) {
    int wid = threadIdx.x >> 6, lane = threadIdx.x & 63;
    int rA = blockIdx.x * 8 + wid * 2;
    if (rA >= n) return;                           // wave-uniform
    int rB = rA + 1;
    bool hasB = rB < n;                            // wave-uniform
    int q = lane >> 4, t = lane & 15;
    const uint4* hb4 = (const uint4*)hb;           // row = 16 uint4: idx = (row<<4)+t
    float accA[8], accB[8];
    #pragma unroll
    for (int i = 0; i < 8; i++) { accA[i] = 0.0f; accB[i] = 0.0f; }
    if (q == 0) {                                  // self-loop A: dis^2 * h[rA]
        float dc = dis[rA];
        uint4 u = hb4[((unsigned)rA << 4) + t];
        float sn = dc * dc;
        accA[0] = sn * bf2f_lo(u.x); accA[1] = sn * bf2f_hi(u.x);
        accA[2] = sn * bf2f_lo(u.y); accA[3] = sn * bf2f_hi(u.y);
        accA[4] = sn * bf2f_lo(u.z); accA[5] = sn * bf2f_hi(u.z);
        accA[6] = sn * bf2f_lo(u.w); accA[7] = sn * bf2f_hi(u.w);
    } else if (q == 1 && hasB) {                   // self-loop B
        float dc = dis[rB];
        uint4 u = hb4[((unsigned)rB << 4) + t];
        float sn = dc * dc;
        accB[0] = sn * bf2f_lo(u.x); accB[1] = sn * bf2f_hi(u.x);
        accB[2] = sn * bf2f_lo(u.y); accB[3] = sn * bf2f_hi(u.y);
        accB[4] = sn * bf2f_lo(u.z); accB[5] = sn * bf2f_hi(u.z);
        accB[6] = sn * bf2f_lo(u.w); accB[7] = sn * bf2f_hi(u.w);
    }
    int s0A = rowptr[rA];
    int lenA = rowptr[rA + 1] - s0A;
    int s0B = 0, lenB = 0;
    if (hasB) { s0B = rowptr[rB]; lenB = rowptr[rB + 1] - s0B; }
    int lenM = lenA > lenB ? lenA : lenB;
    for (int base = 0; base < lenM; base += 64) {
        int idx = base + lane;
        int svA = 0; float wvA = 0.0f;             // pads: row 0, weight 0
        if (idx < lenA) {
            long long p = __builtin_nontemporal_load(srcs2 + s0A + idx);
            svA = (int)(unsigned)(p & 0xffffffffll);
            wvA = __uint_as_float((unsigned)((unsigned long long)p >> 32));
        }
        int svB = 0; float wvB = 0.0f;
        if (idx < lenB) {
            long long p = __builtin_nontemporal_load(srcs2 + s0B + idx);
            svB = (int)(unsigned)(p & 0xffffffffll);
            wvB = __uint_as_float((unsigned)((unsigned long long)p >> 32));
        }
        int mA = lenA - base; if (mA < 0) mA = 0; if (mA > 64) mA = 64;
        int mB = lenB - base; if (mB < 0) mB = 0; if (mB > 64) mB = 64;
        int kA = (mA + 3) >> 2, kB = (mB + 3) >> 2;
        int kM = kA > kB ? kA : kB;                // 0..16, wave-uniform
        int gcount = (kM + 3) >> 2;                // groups of 4 slots/quad
        for (int gg = 0; gg < gcount; gg++) {      // wave-uniform trip count
            int jb = q + (gg << 4);                // jb+12 <= 63
            int a0 = __shfl(svA, jb, 64);
            int a1 = __shfl(svA, jb + 4, 64);
            int a2 = __shfl(svA, jb + 8, 64);
            int a3 = __shfl(svA, jb + 12, 64);
            float x0 = __shfl(wvA, jb, 64);        // 0 for pad slots
            float x1 = __shfl(wvA, jb + 4, 64);
            float x2 = __shfl(wvA, jb + 8, 64);
            float x3 = __shfl(wvA, jb + 12, 64);
            int b0 = __shfl(svB, jb, 64);
            int b1 = __shfl(svB, jb + 4, 64);
            int b2 = __shfl(svB, jb + 8, 64);
            int b3 = __shfl(svB, jb + 12, 64);
            float y0 = __shfl(wvB, jb, 64);
            float y1 = __shfl(wvB, jb + 4, 64);
            float y2 = __shfl(wvB, jb + 8, 64);
            float y3 = __shfl(wvB, jb + 12, 64);
            // 8 independent gathers in flight before any consume
            uint4 uA0 = hb4[((unsigned)a0 << 4) + t];
            uint4 uA1 = hb4[((unsigned)a1 << 4) + t];
            uint4 uA2 = hb4[((unsigned)a2 << 4) + t];
            uint4 uA3 = hb4[((unsigned)a3 << 4) + t];
            uint4 uB0 = hb4[((unsigned)b0 << 4) + t];
            uint4 uB1 = hb4[((unsigned)b1 << 4) + t];
            uint4 uB2 = hb4[((unsigned)b2 << 4) + t];
            uint4 uB3 = hb4[((unsigned)b3 << 4) + t];
            accA[0] += x0 * bf2f_lo(uA0.x); accA[1] += x0 * bf2f_hi(uA0.x);
            accA[2] += x0 * bf2f_lo(uA0.y); accA[3] += x0 * bf2f_hi(uA0.y);
            accA[4] += x0 * bf2f_lo(uA0.z); accA[5] += x0 * bf2f_hi(uA0.z);
            accA[6] += x0 * bf2f_lo(uA0.w); accA[7] += x0 * bf2f_hi(uA0.w);
            accA[0] += x1 * bf2f_lo(uA1.x); accA[1] += x1 * bf2f_hi(uA1.x);
            accA[2] += x1 * bf2f_lo(uA1.y); accA[3] += x1 * bf2f_hi(uA1.y);
            accA[4] += x1 * bf2f_lo(uA1.z); accA[5] += x1 * bf2f_hi(uA1.z);
            accA[6] += x1 * bf2f_lo(uA1.w); accA[7] += x1 * bf2f_hi(uA1.w);
            accA[0] += x2 * bf2f_lo(uA2.x); accA[1] += x2 * bf2f_hi(uA2.x);
            accA[2] += x2 * bf2f_lo(uA2.y); accA[3] += x2 * bf2f_hi(uA2.y);
            accA[4] += x2 * bf2f_lo(uA2.z); accA[5] += x2 * bf2f_hi(uA2.z);
            accA[6] += x2 * bf2f_lo(uA2.w); accA[7] += x2 * bf2f_hi(uA2.w);
            accA[0] += x3 * bf2f_lo(uA3.x); accA[1] += x3 * bf2f_hi(uA3.x);
            accA[2] += x3 * bf2f_lo(uA3.y); accA[3] += x3 * bf2f_hi(uA3.y);
            accA[4] += x3 * bf2f_lo(uA3.z); accA[5] += x3 * bf2f_hi(uA3.z);
            accA[6] += x3 * bf2f_lo(uA3.w); accA[7] += x3 * bf2f_hi(uA3.w);
            accB[0] += y0 * bf2f_lo(uB0.x); accB[1] += y0 * bf2f_hi(uB0.x);
            accB[2] += y0 * bf2f_lo(uB0.y); accB[3] += y0 * bf2f_hi(uB0.y);
            accB[4] += y0 * bf2f_lo(uB0.z); accB[5] += y0 * bf2f_hi(uB0.z);
            accB[6] += y0 * bf2f_lo(uB0.w); accB[7] += y0 * bf2f_hi(uB0.w);
            accB[0] += y1 * bf2f_lo(uB1.x); accB[1] += y1 * bf2f_hi(uB1.x);
            accB[2] += y1 * bf2f_lo(uB1.y); accB[3] += y1 * bf2f_hi(uB1.y);
            accB[4] += y1 * bf2f_lo(uB1.z); accB[5] += y1 * bf2f_hi(uB1.z);
            accB[6] += y1 * bf2f_lo(uB1.w); accB[7] += y1 * bf2f_hi(uB1.w);
            accB[0] += y2 * bf2f_lo(uB2.x); accB[1] += y2 * bf2f_hi(uB2.x);
            accB[2] += y2 * bf2f_lo(uB2.y); accB[3] += y2 * bf2f_hi(uB2.y);
            accB[4] += y2 * bf2f_lo(uB2.z); accB[5] += y2 * bf2f_hi(uB2.z);
            accB[6] += y2 * bf2f_lo(uB2.w); accB[7] += y2 * bf2f_hi(uB2.w);
            accB[0] += y3 * bf2f_lo(uB3.x); accB[1] += y3 * bf2f_hi(uB3.x);
            accB[2] += y3 * bf2f_lo(uB3.y); accB[3] += y3 * bf2f_hi(uB3.y);
            accB[4] += y3 * bf2f_lo(uB3.z); accB[5] += y3 * bf2f_hi(uB3.z);
            accB[6] += y3 * bf2f_lo(uB3.w); accB[7] += y3 * bf2f_hi(uB3.w);
        }
    }
    // combine the 4 quads' partials, then relu (both rows)
    #pragma unroll
    for (int i = 0; i < 8; i++) {
        accA[i] += __shfl_xor(accA[i], 16, 64);
        accA[i] += __shfl_xor(accA[i], 32, 64);
        accA[i] = accA[i] > 0.0f ? accA[i] : 0.0f;
        accB[i] += __shfl_xor(accB[i], 16, 64);
        accB[i] += __shfl_xor(accB[i], 32, 64);
        accB[i] = accB[i] > 0.0f ? accB[i] : 0.0f;
    }
    // LN stats for both rows (full-wave shuffles; every lane gets the stats)
    float s1A = 0.0f, s2A = 0.0f, s1B = 0.0f, s2B = 0.0f;
    #pragma unroll
    for (int i = 0; i < 8; i++) {
        s1A += accA[i]; s2A += accA[i] * accA[i];
        s1B += accB[i]; s2B += accB[i] * accB[i];
    }
    #pragma unroll
    for (int mm = 8; mm >= 1; mm >>= 1) {
        s1A += __shfl_xor(s1A, mm, 64);
        s2A += __shfl_xor(s2A, mm, 64);
        s1B += __shfl_xor(s1B, mm, 64);
        s2B += __shfl_xor(s2B, mm, 64);
    }
    float meanA = s1A * (1.0f / 128.0f);
    float varA  = s2A * (1.0f / 128.0f) - meanA * meanA;
    float rstdA = rsqrtf(varA + 1e-5f);
    float meanB = s1B * (1.0f / 128.0f);
    float varB  = s2B * (1.0f / 128.0f) - meanB * meanB;
    float rstdB = rsqrtf(varB + 1e-5f);
    const f32x4* gr = (const f32x4*)gamma;
    const f32x4* br = (const f32x4*)beta;
    if (q == 0) {                                  // quad 0 stores row A
        const f32x4* xr = (const f32x4*)(x + (size_t)rA * D);
        f32x4* orow = (f32x4*)(out + (size_t)rA * D);
        #pragma unroll
        for (int hf = 0; hf < 2; hf++) {
            f32x4 g = gr[2 * t + hf], b = br[2 * t + hf];
            f32x4 xx = __builtin_nontemporal_load(xr + 2 * t + hf);
            f32x4 o;
            o[0] = (accA[4 * hf + 0] - meanA) * rstdA * g[0] + b[0] + xx[0];
            o[1] = (accA[4 * hf + 1] - meanA) * rstdA * g[1] + b[1] + xx[1];
            o[2] = (accA[4 * hf + 2] - meanA) * rstdA * g[2] + b[2] + xx[2];
            o[3] = (accA[4 * hf + 3] - meanA) * rstdA * g[3] + b[3] + xx[3];
            __builtin_nontemporal_store(o, orow + 2 * t + hf);
        }
    } else if (q == 1 && hasB) {                   // quad 1 stores row B
        const f32x4* xr = (const f32x4*)(x + (size_t)rB * D);
        f32x4* orow = (f32x4*)(out + (size_t)rB * D);
        #pragma unroll
        for (int hf = 0; hf < 2; hf++) {
            f32x4 g = gr[2 * t + hf], b = br[2 * t + hf];
            f32x4 xx = __builtin_nontemporal_load(xr + 2 * t + hf);
            f32x4 o;
            o[0] = (accB[4 * hf + 0] - meanB) * rstdB * g[0] + b[0] + xx[0];
            o[1] = (accB[4 * hf + 1] - meanB) * rstdB * g[1] + b[1] + xx[1];
            o[2] = (accB[4 * hf + 2] - meanB) * rstdB * g[2] + b[2] + xx[2];
            o[3] = (accB[4 * hf + 3] - meanB) * rstdB * g[3] + b[3] + xx[3];
            __builtin_nontemporal_store(o, orow + 2 * t + hf);
        }
    }
}

extern "C" void kernel_launch(void* const* d_in, const int* in_sizes, int n_in,
                              void* d_out, int out_size, void* d_ws, size_t ws_size,
                              hipStream_t stream) {
    const float* x     = (const float*)d_in[0];
    const int*   ei    = (const int*)d_in[1];   // [2, E]
    const float* W     = (const float*)d_in[2];
    const float* bias  = (const float*)d_in[3];
    const float* gamma = (const float*)d_in[4];
    const float* beta  = (const float*)d_in[5];
    int N = in_sizes[0] / D;
    int E = in_sizes[1] / 2;
    int nb  = (N + 255) / 256;                   // 196 scan blocks (<=256)
    int nbE = (E + 255) / 256;                   // 3125
    int K   = (E + CHUNK - 1) >> CHSH;           // 25 chunks / copies
    int gemm_blocks = (N + 255) / 256;           // 196 (256 rows per 1024-thr block)

    char* ws = (char*)d_ws;
    size_t off = 0;
    unsigned short* hb  = (unsigned short*)(ws + off); off += (size_t)N * D * 2;       // 12.8 MB
    unsigned char* degc = (unsigned char*)(ws + off);  off += (size_t)K * N;           // 1.25 MB
    unsigned char* cntc = (unsigned char*)(ws + off);  off += (size_t)K * N;           // 1.25 MB
    float*    dis       = (float*)(ws + off);          off += (size_t)N * 4;
    unsigned* cnt       = (unsigned*)(ws + off);       off += (size_t)N * 4;
    int*      rowptr    = (int*)(ws + off);            off += (size_t)(N + 1) * 4;
    int*      rowptrc   = (int*)(ws + off);            off += (size_t)K * N * 4;       // 5 MB
    unsigned* partial   = (unsigned*)(ws + off);       off += 256 * 4;
    unsigned char* aux  = (unsigned char*)(ws + off);  off += (size_t)E;               // 0.8 MB
    off = (off + 15) & ~(size_t)15;
    long long* srcs2    = (long long*)(ws + off);      off += (size_t)E * 8;           // 6.4 MB
    float*    out       = (float*)d_out;

    k_gemm_hist<<<2 * K + gemm_blocks, 1024, 0, stream>>>(x, W, bias, hb, N,
                                                          ei, E, N, degc, cntc, aux, K);
    k_partial<<<nb, 256, 0, stream>>>(degc, cntc, dis, cnt, partial, N, K);
    k_rowptrc<<<nb, 256, 0, stream>>>(cnt, cntc, partial, N, E, rowptr, rowptrc, K, nb);
    k_fill<<<nbE, 256, 0, stream>>>(ei, E, N, rowptrc, aux, dis, srcs2);
    k_agg<<<(N + 7) / 8, 256, 0, stream>>>(x, hb, dis, rowptr, srcs2, gamma, beta, out, N);
}